// Round 1
// baseline (334.876 us; speedup 1.0000x reference)
//
#include <hip/hip_runtime.h>
#include <hip/hip_bf16.h>

#define B_SZ 2
#define T_SEQ 1024
#define D_MODEL 1024
#define N_HEADS 16
#define TREE_DEPTH 5
#define DH 64

// ---------------------------------------------------------------------------
// Kernel 1: P = sigmoid(x @ Wp + bp)   x:(2048,1024) Wp:(1024,80) -> P:(2048,80)
// one block per token row; stage x row in LDS; threads 0..79 each do one dot.
// ---------------------------------------------------------------------------
__global__ __launch_bounds__(256) void paths_kernel(
    const float* __restrict__ x, const float* __restrict__ Wp,
    const float* __restrict__ bp, float* __restrict__ P)
{
    __shared__ float xs[D_MODEL];
    const int row = blockIdx.x;
    const float* xr = x + (size_t)row * D_MODEL;
    for (int i = threadIdx.x; i < D_MODEL; i += 256) xs[i] = xr[i];
    __syncthreads();
    const int col = threadIdx.x;
    if (col < N_HEADS * TREE_DEPTH) {
        float acc = bp[col];
        const float* w = Wp + col;
        #pragma unroll 8
        for (int k = 0; k < D_MODEL; ++k)
            acc = fmaf(xs[k], w[(size_t)k * (N_HEADS * TREE_DEPTH)], acc);
        P[(size_t)row * (N_HEADS * TREE_DEPTH) + col] = 1.0f / (1.0f + __expf(-acc));
    }
}

// ---------------------------------------------------------------------------
// Kernel 2: generic fp32 GEMM  C = A(MxK) @ B(KxN), tiles 64x64, BK=16,
// 256 threads, 4x4 microtile per thread.
// ---------------------------------------------------------------------------
__global__ __launch_bounds__(256) void gemm64(
    const float* __restrict__ A, const float* __restrict__ Bm,
    float* __restrict__ C, int M, int N, int K)
{
    __shared__ float As[16][68];   // As[k][m]  (transposed), row stride 272B (16B aligned)
    __shared__ float Bs[16][68];   // Bs[k][n]
    const int tid = threadIdx.x;
    const int tx = tid & 15, ty = tid >> 4;
    const int rowBase = blockIdx.y * 64;
    const int colBase = blockIdx.x * 64;

    // load assignments
    const int lr  = tid >> 2;          // 0..63 : A-tile row
    const int lk4 = (tid & 3) * 4;     // k offset (float4)
    const int bk  = tid >> 4;          // 0..15 : B-tile k row
    const int bn4 = (tid & 15) * 4;    // n offset (float4)

    float acc[4][4];
    #pragma unroll
    for (int i = 0; i < 4; ++i)
        #pragma unroll
        for (int j = 0; j < 4; ++j) acc[i][j] = 0.0f;

    for (int k0 = 0; k0 < K; k0 += 16) {
        float4 av = *(const float4*)(A + (size_t)(rowBase + lr) * K + k0 + lk4);
        float4 bv = *(const float4*)(Bm + (size_t)(k0 + bk) * N + colBase + bn4);
        __syncthreads();               // previous iteration's compute done
        As[lk4 + 0][lr] = av.x;
        As[lk4 + 1][lr] = av.y;
        As[lk4 + 2][lr] = av.z;
        As[lk4 + 3][lr] = av.w;
        *(float4*)&Bs[bk][bn4] = bv;
        __syncthreads();
        #pragma unroll
        for (int kk = 0; kk < 16; ++kk) {
            float4 a = *(const float4*)&As[kk][ty * 4];
            float4 b = *(const float4*)&Bs[kk][tx * 4];
            const float ar[4] = {a.x, a.y, a.z, a.w};
            const float br[4] = {b.x, b.y, b.z, b.w};
            #pragma unroll
            for (int i = 0; i < 4; ++i)
                #pragma unroll
                for (int j = 0; j < 4; ++j)
                    acc[i][j] = fmaf(ar[i], br[j], acc[i][j]);
        }
    }
    #pragma unroll
    for (int i = 0; i < 4; ++i) {
        float* crow = C + (size_t)(rowBase + ty * 4 + i) * N + colBase + tx * 4;
        *(float4*)crow = make_float4(acc[i][0], acc[i][1], acc[i][2], acc[i][3]);
    }
}

// ---------------------------------------------------------------------------
// Kernel 3: attention.  grid = (qtile=16, b*H=32), block 256.
// thread owns (q = tid>>2, dim chunk sub*16..+15, score chunk sub*16..+15).
// scores in (0,1] -> no softmax max needed.
// ---------------------------------------------------------------------------
__global__ __launch_bounds__(256) void attn64(
    const float* __restrict__ P, const float* __restrict__ V,
    float* __restrict__ ctx)
{
    const int bh = blockIdx.y;
    const int b = bh >> 4, h = bh & 15;
    const int qt = blockIdx.x;
    const int tid = threadIdx.x;
    const int qg = tid >> 2;     // local q 0..63
    const int sub = tid & 3;     // 0..3

    __shared__ float pk_s[64][5];
    __shared__ float w_s[64][68];
    __shared__ float V_s[64][68];

    const int qglob = qt * 64 + qg;
    const float* prow = P + ((size_t)(b * T_SEQ + qglob)) * 80 + h * 5;
    const float pq0 = prow[0], pq1 = prow[1], pq2 = prow[2], pq3 = prow[3], pq4 = prow[4];

    float c[16];
    #pragma unroll
    for (int i = 0; i < 16; ++i) c[i] = 0.0f;
    float dpart = 0.0f;

    for (int kt = 0; kt <= qt; ++kt) {
        __syncthreads();   // previous phase-B reads done before overwrite
        const int kbase = b * T_SEQ + kt * 64;
        // load pk tile (64x5)
        for (int i = tid; i < 64 * 5; i += 256) {
            int r = i / 5, j = i - r * 5;
            pk_s[r][j] = P[(size_t)(kbase + r) * 80 + h * 5 + j];
        }
        // load V tile (64x64)
        #pragma unroll
        for (int i = 0; i < 4; ++i) {
            int r = (tid >> 4) + i * 16;
            int c4 = (tid & 15);
            *(float4*)&V_s[r][c4 * 4] =
                *(const float4*)(V + (size_t)(kbase + r) * D_MODEL + h * DH + c4 * 4);
        }
        __syncthreads();
        // phase A: scores for (qg, k = sub*16 + kk)
        #pragma unroll
        for (int kk = 0; kk < 16; ++kk) {
            const int kl = sub * 16 + kk;
            const float k0 = pk_s[kl][0], k1 = pk_s[kl][1], k2 = pk_s[kl][2],
                        k3 = pk_s[kl][3], k4 = pk_s[kl][4];
            // agree = 1 - pq - pk + 2 pq pk ; cumprod-sum
            float a, cp, s;
            a = fmaf(2.0f * pq0, k0, 1.0f - pq0 - k0); cp = a;      s = cp;
            a = fmaf(2.0f * pq1, k1, 1.0f - pq1 - k1); cp *= a;     s += cp;
            a = fmaf(2.0f * pq2, k2, 1.0f - pq2 - k2); cp *= a;     s += cp;
            a = fmaf(2.0f * pq3, k3, 1.0f - pq3 - k3); cp *= a;     s += cp;
            a = fmaf(2.0f * pq4, k4, 1.0f - pq4 - k4); cp *= a;     s += cp;
            const float sim = s * 0.2f;
            const int kglob = kt * 64 + kl;
            const float w = (kglob <= qglob) ? __expf(sim) : 0.0f;
            w_s[qg][kl] = w;
            dpart += w;
        }
        __syncthreads();
        // phase B: ctx += w * V
        for (int k = 0; k < 64; ++k) {
            const float wv = w_s[qg][k];
            const float4* vr = (const float4*)&V_s[k][sub * 16];
            const float4 v0 = vr[0], v1 = vr[1], v2 = vr[2], v3 = vr[3];
            c[0]  = fmaf(wv, v0.x, c[0]);  c[1]  = fmaf(wv, v0.y, c[1]);
            c[2]  = fmaf(wv, v0.z, c[2]);  c[3]  = fmaf(wv, v0.w, c[3]);
            c[4]  = fmaf(wv, v1.x, c[4]);  c[5]  = fmaf(wv, v1.y, c[5]);
            c[6]  = fmaf(wv, v1.z, c[6]);  c[7]  = fmaf(wv, v1.w, c[7]);
            c[8]  = fmaf(wv, v2.x, c[8]);  c[9]  = fmaf(wv, v2.y, c[9]);
            c[10] = fmaf(wv, v2.z, c[10]); c[11] = fmaf(wv, v2.w, c[11]);
            c[12] = fmaf(wv, v3.x, c[12]); c[13] = fmaf(wv, v3.y, c[13]);
            c[14] = fmaf(wv, v3.z, c[14]); c[15] = fmaf(wv, v3.w, c[15]);
        }
    }
    // reduce denom over sub (4 adjacent lanes, same wave)
    dpart += __shfl_xor(dpart, 1);
    dpart += __shfl_xor(dpart, 2);
    const float inv = 1.0f / dpart;

    float* orow = ctx + (size_t)(b * T_SEQ + qglob) * D_MODEL + h * DH + sub * 16;
    #pragma unroll
    for (int i = 0; i < 4; ++i) {
        float4 o = make_float4(c[i * 4 + 0] * inv, c[i * 4 + 1] * inv,
                               c[i * 4 + 2] * inv, c[i * 4 + 3] * inv);
        ((float4*)orow)[i] = o;
    }
}

// ---------------------------------------------------------------------------
extern "C" void kernel_launch(void* const* d_in, const int* in_sizes, int n_in,
                              void* d_out, int out_size, void* d_ws, size_t ws_size,
                              hipStream_t stream)
{
    const float* x  = (const float*)d_in[0];
    const float* Wp = (const float*)d_in[1];
    const float* bp = (const float*)d_in[2];
    const float* Wv = (const float*)d_in[3];
    const float* Wo = (const float*)d_in[4];
    float* out = (float*)d_out;

    const int M = B_SZ * T_SEQ;            // 2048
    float* P   = (float*)d_ws;                                  // 2048*80*4 = 640KB
    float* V   = (float*)((char*)d_ws + (1u << 20));            // 8MB
    float* ctx = (float*)((char*)d_ws + (1u << 20) + (8u << 20)); // 8MB

    paths_kernel<<<M, 256, 0, stream>>>(x, Wp, bp, P);
    gemm64<<<dim3(D_MODEL / 64, M / 64), 256, 0, stream>>>(x, Wv, V, M, D_MODEL, D_MODEL);
    attn64<<<dim3(T_SEQ / 64, B_SZ * N_HEADS), 256, 0, stream>>>(P, V, ctx);
    gemm64<<<dim3(D_MODEL / 64, M / 64), 256, 0, stream>>>(ctx, Wo, out, M, D_MODEL, D_MODEL);
}

// Round 2
// 245.326 us; speedup vs baseline: 1.3650x; 1.3650x over previous
//
#include <hip/hip_runtime.h>
#include <hip/hip_bf16.h>

#define B_SZ 2
#define T_SEQ 1024
#define D_MODEL 1024
#define N_HEADS 16
#define TREE_DEPTH 5
#define DH 64

typedef __attribute__((ext_vector_type(8))) short short8;
typedef __attribute__((ext_vector_type(4))) float f32x4;

// round-to-nearest-even fp32 -> bf16 (avoid truncation bias)
__device__ __forceinline__ ushort f2bf(float f) {
    uint32_t u = __float_as_uint(f);
    u += 0x7FFFu + ((u >> 16) & 1u);
    return (ushort)(u >> 16);
}

// ---------------------------------------------------------------------------
// convert fp32 -> bf16, 8 elems/thread
// ---------------------------------------------------------------------------
__global__ __launch_bounds__(256) void convert_bf16(
    const float* __restrict__ in, ushort* __restrict__ out)
{
    const int i = (blockIdx.x * 256 + threadIdx.x) * 8;
    const float4 a = *(const float4*)(in + i);
    const float4 b = *(const float4*)(in + i + 4);
    ushort o[8] = {f2bf(a.x), f2bf(a.y), f2bf(a.z), f2bf(a.w),
                   f2bf(b.x), f2bf(b.y), f2bf(b.z), f2bf(b.w)};
    *(uint4*)(out + i) = *(const uint4*)o;
}

// ---------------------------------------------------------------------------
// transpose + convert: W (K x N fp32, row-major) -> Wt (N x K bf16, row-major)
// 32x32 tiles, grid (N/32, K/32), 256 threads
// ---------------------------------------------------------------------------
__global__ __launch_bounds__(256) void transpose_bf16(
    const float* __restrict__ W, ushort* __restrict__ Wt, int K, int N)
{
    __shared__ float tile[32][33];
    const int n0 = blockIdx.x * 32, k0 = blockIdx.y * 32;
    const int tx = threadIdx.x & 31, ty = threadIdx.x >> 5; // ty 0..7
    #pragma unroll
    for (int i = 0; i < 4; ++i)
        tile[ty + i * 8][tx] = W[(size_t)(k0 + ty + i * 8) * N + n0 + tx];
    __syncthreads();
    #pragma unroll
    for (int i = 0; i < 4; ++i)
        Wt[(size_t)(n0 + ty + i * 8) * K + k0 + tx] = f2bf(tile[tx][ty + i * 8]);
}

// ---------------------------------------------------------------------------
// paths: P = sigmoid(x @ Wp + bp)  (fp32, small)
// ---------------------------------------------------------------------------
__global__ __launch_bounds__(256) void paths_kernel(
    const float* __restrict__ x, const float* __restrict__ Wp,
    const float* __restrict__ bp, float* __restrict__ P)
{
    __shared__ float xs[D_MODEL];
    const int row = blockIdx.x;
    const float* xr = x + (size_t)row * D_MODEL;
    for (int i = threadIdx.x; i < D_MODEL; i += 256) xs[i] = xr[i];
    __syncthreads();
    const int col = threadIdx.x;
    if (col < N_HEADS * TREE_DEPTH) {
        float acc = bp[col];
        const float* w = Wp + col;
        #pragma unroll 8
        for (int k = 0; k < D_MODEL; ++k)
            acc = fmaf(xs[k], w[(size_t)k * (N_HEADS * TREE_DEPTH)], acc);
        P[(size_t)row * (N_HEADS * TREE_DEPTH) + col] = 1.0f / (1.0f + __expf(-acc));
    }
}

// ---------------------------------------------------------------------------
// bf16 MFMA GEMM: C(MxN fp32) = A(MxK bf16 rowmajor) @ Bt(NxK bf16 rowmajor)^T
// BM=128, BN=64, BK=32. 256 threads = 4 waves (2x2 wave grid: 64m x 32n each).
// LDS in MFMA fragment order: per 16-row block, lane l holds 16B at block*1024+l*16.
// ---------------------------------------------------------------------------
__global__ __launch_bounds__(256) void gemm_bf16(
    const ushort* __restrict__ A, const ushort* __restrict__ Bt,
    float* __restrict__ C, int M, int N, int K)
{
    __shared__ ushort As[128 * 32];  // 8 mb blocks * 512 ushorts
    __shared__ ushort Bs[64 * 32];   // 4 nb blocks * 512 ushorts

    const int tid = threadIdx.x;
    const int lane = tid & 63;
    const int w = tid >> 6;
    const int wm = w & 1, wn = w >> 1;
    const int rowBase = blockIdx.y * 128;
    const int colBase = blockIdx.x * 64;

    // staging assignments
    const int quad = tid & 3;            // k-chunk (8 bf16)
    const int arow0 = tid >> 2;          // A rows 0..63 (iter0), +64 (iter1)
    const int brow = tid >> 2;           // B rows 0..63

    // LDS write offsets (fragment order)
    const int am0 = arow0, am1 = arow0 + 64;
    const int aoff0 = (am0 >> 4) * 512 + (quad * 16 + (am0 & 15)) * 8;
    const int aoff1 = (am1 >> 4) * 512 + (quad * 16 + (am1 & 15)) * 8;
    const int boff  = (brow >> 4) * 512 + (quad * 16 + (brow & 15)) * 8;

    const ushort* Ap0 = A + (size_t)(rowBase + am0) * K + quad * 8;
    const ushort* Ap1 = A + (size_t)(rowBase + am1) * K + quad * 8;
    const ushort* Bp  = Bt + (size_t)(colBase + brow) * K + quad * 8;

    f32x4 acc[4][2];
    #pragma unroll
    for (int i = 0; i < 4; ++i) {
        acc[i][0] = (f32x4)0.0f;
        acc[i][1] = (f32x4)0.0f;
    }

    const int niter = K / 32;
    uint4 ga0 = *(const uint4*)Ap0;
    uint4 ga1 = *(const uint4*)Ap1;
    uint4 gb  = *(const uint4*)Bp;

    for (int it = 0; it < niter; ++it) {
        __syncthreads();
        *(uint4*)(As + aoff0) = ga0;
        *(uint4*)(As + aoff1) = ga1;
        *(uint4*)(Bs + boff)  = gb;
        __syncthreads();
        if (it + 1 < niter) {
            ga0 = *(const uint4*)(Ap0 + (it + 1) * 32);
            ga1 = *(const uint4*)(Ap1 + (it + 1) * 32);
            gb  = *(const uint4*)(Bp  + (it + 1) * 32);
        }
        short8 af[4], bf[2];
        #pragma unroll
        for (int j = 0; j < 4; ++j)
            af[j] = *(const short8*)(As + (wm * 4 + j) * 512 + lane * 8);
        #pragma unroll
        for (int j = 0; j < 2; ++j)
            bf[j] = *(const short8*)(Bs + (wn * 2 + j) * 512 + lane * 8);
        #pragma unroll
        for (int i = 0; i < 4; ++i)
            #pragma unroll
            for (int j = 0; j < 2; ++j)
                acc[i][j] = __builtin_amdgcn_mfma_f32_16x16x32_bf16(
                    af[i], bf[j], acc[i][j], 0, 0, 0);
    }

    // C/D layout: col = lane&15, row = (lane>>4)*4 + reg
    const int cq = lane >> 4, cl = lane & 15;
    #pragma unroll
    for (int i = 0; i < 4; ++i)
        #pragma unroll
        for (int j = 0; j < 2; ++j) {
            const int col = colBase + wn * 32 + j * 16 + cl;
            #pragma unroll
            for (int r = 0; r < 4; ++r) {
                const int row = rowBase + wm * 64 + i * 16 + cq * 4 + r;
                C[(size_t)row * N + col] = acc[i][j][r];
            }
        }
}

// ---------------------------------------------------------------------------
// attention: paired q-tiles (qt, 15-qt) for balance, dh split in halves.
// grid (8, 64): y = bh*2 + half. 256 threads: qg = tid>>2 (64 q), sub = tid&3
// (8 dims each). Writes ctx directly as bf16.
// ---------------------------------------------------------------------------
__global__ __launch_bounds__(256) void attn_kernel(
    const float* __restrict__ P, const float* __restrict__ V,
    ushort* __restrict__ ctxb)
{
    const int half = blockIdx.y & 1;
    const int bh = blockIdx.y >> 1;
    const int b = bh >> 4, h = bh & 15;
    const int pair = blockIdx.x;
    const int tid = threadIdx.x;
    const int qg = tid >> 2, sub = tid & 3;

    __shared__ float pk_s[64][5];
    __shared__ float w_s[64][68];
    __shared__ float V_s[64][36];

    for (int pi = 0; pi < 2; ++pi) {
        const int qt = pi ? (15 - pair) : pair;
        const int qglob = qt * 64 + qg;
        const float* prow = P + (size_t)(b * T_SEQ + qglob) * 80 + h * 5;
        const float pq0 = prow[0], pq1 = prow[1], pq2 = prow[2],
                    pq3 = prow[3], pq4 = prow[4];

        float c[8];
        #pragma unroll
        for (int i = 0; i < 8; ++i) c[i] = 0.0f;
        float dpart = 0.0f;

        for (int kt = 0; kt <= qt; ++kt) {
            __syncthreads();
            const int kbase = b * T_SEQ + kt * 64;
            // stage pk (64x5)
            for (int i = tid; i < 320; i += 256) {
                int r = i / 5, j = i - r * 5;
                pk_s[r][j] = P[(size_t)(kbase + r) * 80 + h * 5 + j];
            }
            // stage V half-tile (64 x 32)
            #pragma unroll
            for (int i = 0; i < 2; ++i) {
                const int idx = tid + i * 256;
                const int r = idx >> 3, c4 = (idx & 7) * 4;
                *(float4*)&V_s[r][c4] =
                    *(const float4*)(V + (size_t)(kbase + r) * D_MODEL +
                                     h * DH + half * 32 + c4);
            }
            __syncthreads();
            // phase A: 16 scores per thread, kl = kk*4+sub (bank-friendly)
            #pragma unroll
            for (int kk = 0; kk < 16; ++kk) {
                const int kl = kk * 4 + sub;
                const float k0 = pk_s[kl][0], k1 = pk_s[kl][1], k2 = pk_s[kl][2],
                            k3 = pk_s[kl][3], k4 = pk_s[kl][4];
                float a, cp, s;
                a = fmaf(2.0f * pq0, k0, 1.0f - pq0 - k0); cp = a;  s = cp;
                a = fmaf(2.0f * pq1, k1, 1.0f - pq1 - k1); cp *= a; s += cp;
                a = fmaf(2.0f * pq2, k2, 1.0f - pq2 - k2); cp *= a; s += cp;
                a = fmaf(2.0f * pq3, k3, 1.0f - pq3 - k3); cp *= a; s += cp;
                a = fmaf(2.0f * pq4, k4, 1.0f - pq4 - k4); cp *= a; s += cp;
                const float sim = s * 0.2f;
                const int kglob = kt * 64 + kl;
                const float wv = (kglob <= qglob) ? __expf(sim) : 0.0f;
                w_s[qg][kl] = wv;
                dpart += wv;
            }
            __syncthreads();
            // phase B: c += w * V over 64 keys
            for (int k = 0; k < 64; ++k) {
                const float wv = w_s[qg][k];
                const float4 v0 = *(const float4*)&V_s[k][sub * 8];
                const float4 v1 = *(const float4*)&V_s[k][sub * 8 + 4];
                c[0] = fmaf(wv, v0.x, c[0]); c[1] = fmaf(wv, v0.y, c[1]);
                c[2] = fmaf(wv, v0.z, c[2]); c[3] = fmaf(wv, v0.w, c[3]);
                c[4] = fmaf(wv, v1.x, c[4]); c[5] = fmaf(wv, v1.y, c[5]);
                c[6] = fmaf(wv, v1.z, c[6]); c[7] = fmaf(wv, v1.w, c[7]);
            }
        }
        dpart += __shfl_xor(dpart, 1);
        dpart += __shfl_xor(dpart, 2);
        const float inv = 1.0f / dpart;

        ushort o[8];
        #pragma unroll
        for (int j = 0; j < 8; ++j) o[j] = f2bf(c[j] * inv);
        *(uint4*)(ctxb + (size_t)(b * T_SEQ + qglob) * D_MODEL +
                  h * DH + half * 32 + sub * 8) = *(const uint4*)o;
    }
}

// ---------------------------------------------------------------------------
extern "C" void kernel_launch(void* const* d_in, const int* in_sizes, int n_in,
                              void* d_out, int out_size, void* d_ws, size_t ws_size,
                              hipStream_t stream)
{
    const float* x  = (const float*)d_in[0];
    const float* Wp = (const float*)d_in[1];
    const float* bp = (const float*)d_in[2];
    const float* Wv = (const float*)d_in[3];
    const float* Wo = (const float*)d_in[4];
    float* out = (float*)d_out;

    const int M = B_SZ * T_SEQ;  // 2048
    char* ws = (char*)d_ws;
    float*  P    = (float*) (ws);                       // 640 KB
    ushort* xb   = (ushort*)(ws + (1u  << 20));         // 4 MB
    ushort* Wvt  = (ushort*)(ws + (5u  << 20));         // 2 MB
    ushort* Wot  = (ushort*)(ws + (7u  << 20));         // 2 MB
    float*  V    = (float*) (ws + (9u  << 20));         // 8 MB
    ushort* ctxb = (ushort*)(ws + (17u << 20));         // 4 MB

    convert_bf16<<<M * D_MODEL / (256 * 8), 256, 0, stream>>>(x, xb);
    transpose_bf16<<<dim3(32, 32), 256, 0, stream>>>(Wv, Wvt, D_MODEL, D_MODEL);
    transpose_bf16<<<dim3(32, 32), 256, 0, stream>>>(Wo, Wot, D_MODEL, D_MODEL);
    paths_kernel<<<M, 256, 0, stream>>>(x, Wp, bp, P);

    gemm_bf16<<<dim3(D_MODEL / 64, M / 128), 256, 0, stream>>>(
        xb, Wvt, V, M, D_MODEL, D_MODEL);
    attn_kernel<<<dim3(8, 64), 256, 0, stream>>>(P, V, ctxb);
    gemm_bf16<<<dim3(D_MODEL / 64, M / 128), 256, 0, stream>>>(
        ctxb, Wot, out, M, D_MODEL, D_MODEL);
}

// Round 3
// 188.767 us; speedup vs baseline: 1.7740x; 1.2996x over previous
//
#include <hip/hip_runtime.h>
#include <hip/hip_bf16.h>

#define B_SZ 2
#define T_SEQ 1024
#define D_MODEL 1024
#define N_HEADS 16
#define TREE_DEPTH 5
#define DH 64

typedef __attribute__((ext_vector_type(8))) short short8;
typedef __attribute__((ext_vector_type(4))) float f32x4;

__device__ __forceinline__ ushort f2bf(float f) {
    uint32_t u = __float_as_uint(f);
    u += 0x7FFFu + ((u >> 16) & 1u);
    return (ushort)(u >> 16);
}

// ---------------------------------------------------------------------------
// fp32 -> bf16, 8 elems/thread
// ---------------------------------------------------------------------------
__global__ __launch_bounds__(256) void convert_bf16(
    const float* __restrict__ in, ushort* __restrict__ out)
{
    const int i = (blockIdx.x * 256 + threadIdx.x) * 8;
    const float4 a = *(const float4*)(in + i);
    const float4 b = *(const float4*)(in + i + 4);
    ushort o[8] = {f2bf(a.x), f2bf(a.y), f2bf(a.z), f2bf(a.w),
                   f2bf(b.x), f2bf(b.y), f2bf(b.z), f2bf(b.w)};
    *(uint4*)(out + i) = *(const uint4*)o;
}

// ---------------------------------------------------------------------------
// W (K x N fp32) -> Wt (N x K bf16)
// ---------------------------------------------------------------------------
__global__ __launch_bounds__(256) void transpose_bf16(
    const float* __restrict__ W, ushort* __restrict__ Wt, int K, int N)
{
    __shared__ float tile[32][33];
    const int n0 = blockIdx.x * 32, k0 = blockIdx.y * 32;
    const int tx = threadIdx.x & 31, ty = threadIdx.x >> 5;
    #pragma unroll
    for (int i = 0; i < 4; ++i)
        tile[ty + i * 8][tx] = W[(size_t)(k0 + ty + i * 8) * N + n0 + tx];
    __syncthreads();
    #pragma unroll
    for (int i = 0; i < 4; ++i)
        Wt[(size_t)(n0 + ty + i * 8) * K + k0 + tx] = f2bf(tile[tx][ty + i * 8]);
}

// ---------------------------------------------------------------------------
// phi: per token row, compute 80 sigmoid path probs, expand to 62-dim
// tensor-product features per head, pad to 64, write bf16.
// Phi layout: [(b*16+h)*1024 + t][64]
// ---------------------------------------------------------------------------
__global__ __launch_bounds__(256) void phi_kernel(
    const float* __restrict__ x, const float* __restrict__ Wp,
    const float* __restrict__ bp, ushort* __restrict__ Phi)
{
    __shared__ float xs[D_MODEL];
    __shared__ float p_s[80];
    const int row = blockIdx.x;              // b*1024 + t
    const int tid = threadIdx.x;
    const float* xr = x + (size_t)row * D_MODEL;
    for (int i = tid; i < D_MODEL; i += 256) xs[i] = xr[i];
    __syncthreads();
    if (tid < 80) {
        float acc = bp[tid];
        const float* wp = Wp + tid;
        #pragma unroll 8
        for (int k = 0; k < D_MODEL; ++k)
            acc = fmaf(xs[k], wp[(size_t)k * 80], acc);
        p_s[tid] = 1.0f / (1.0f + __expf(-acc));
    }
    __syncthreads();
    const int b = row >> 10, t = row & 1023;
    #pragma unroll
    for (int i = 0; i < 4; ++i) {
        const int idx = tid + i * 256;       // 0..1023
        const int h = idx >> 6, f = idx & 63;
        float val = 0.0f;
        if (f < 62) {
            int d, off;
            if (f < 2)       { d = 1; off = 0; }
            else if (f < 6)  { d = 2; off = 2; }
            else if (f < 14) { d = 3; off = 6; }
            else if (f < 30) { d = 4; off = 14; }
            else             { d = 5; off = 30; }
            const int e = f - off;
            float prod = 1.0f;
            for (int j = 1; j <= d; ++j) {
                const float p = p_s[h * 5 + j - 1];
                prod *= ((e >> (d - j)) & 1) ? (1.0f - p) : p;
            }
            val = prod;
        }
        Phi[((size_t)(b * 16 + h) * 1024 + t) * 64 + f] = f2bf(val);
    }
}

// ---------------------------------------------------------------------------
// bf16 MFMA GEMM: C(MxN) = A(MxK bf16) @ Bt(NxK bf16)^T
// BM=128, BN=64, BK=32; 4 waves. OUT_BF16 selects ushort vs float output.
// ---------------------------------------------------------------------------
template <bool OUT_BF16>
__global__ __launch_bounds__(256) void gemm_bf16(
    const ushort* __restrict__ A, const ushort* __restrict__ Bt,
    void* __restrict__ Cv, int M, int N, int K)
{
    __shared__ ushort As[128 * 32];
    __shared__ ushort Bs[64 * 32];

    const int tid = threadIdx.x;
    const int lane = tid & 63;
    const int w = tid >> 6;
    const int wm = w & 1, wn = w >> 1;
    const int rowBase = blockIdx.y * 128;
    const int colBase = blockIdx.x * 64;

    const int quad = tid & 3;
    const int arow0 = tid >> 2;
    const int brow = tid >> 2;

    const int am0 = arow0, am1 = arow0 + 64;
    const int aoff0 = (am0 >> 4) * 512 + (quad * 16 + (am0 & 15)) * 8;
    const int aoff1 = (am1 >> 4) * 512 + (quad * 16 + (am1 & 15)) * 8;
    const int boff  = (brow >> 4) * 512 + (quad * 16 + (brow & 15)) * 8;

    const ushort* Ap0 = A + (size_t)(rowBase + am0) * K + quad * 8;
    const ushort* Ap1 = A + (size_t)(rowBase + am1) * K + quad * 8;
    const ushort* Bp  = Bt + (size_t)(colBase + brow) * K + quad * 8;

    f32x4 acc[4][2];
    #pragma unroll
    for (int i = 0; i < 4; ++i) {
        acc[i][0] = (f32x4)0.0f;
        acc[i][1] = (f32x4)0.0f;
    }

    const int niter = K / 32;
    uint4 ga0 = *(const uint4*)Ap0;
    uint4 ga1 = *(const uint4*)Ap1;
    uint4 gb  = *(const uint4*)Bp;

    for (int it = 0; it < niter; ++it) {
        __syncthreads();
        *(uint4*)(As + aoff0) = ga0;
        *(uint4*)(As + aoff1) = ga1;
        *(uint4*)(Bs + boff)  = gb;
        __syncthreads();
        if (it + 1 < niter) {
            ga0 = *(const uint4*)(Ap0 + (it + 1) * 32);
            ga1 = *(const uint4*)(Ap1 + (it + 1) * 32);
            gb  = *(const uint4*)(Bp  + (it + 1) * 32);
        }
        short8 af[4], bf[2];
        #pragma unroll
        for (int j = 0; j < 4; ++j)
            af[j] = *(const short8*)(As + (wm * 4 + j) * 512 + lane * 8);
        #pragma unroll
        for (int j = 0; j < 2; ++j)
            bf[j] = *(const short8*)(Bs + (wn * 2 + j) * 512 + lane * 8);
        #pragma unroll
        for (int i = 0; i < 4; ++i)
            #pragma unroll
            for (int j = 0; j < 2; ++j)
                acc[i][j] = __builtin_amdgcn_mfma_f32_16x16x32_bf16(
                    af[i], bf[j], acc[i][j], 0, 0, 0);
    }

    const int cq = lane >> 4, cl = lane & 15;
    #pragma unroll
    for (int i = 0; i < 4; ++i)
        #pragma unroll
        for (int j = 0; j < 2; ++j) {
            const int col = colBase + wn * 32 + j * 16 + cl;
            #pragma unroll
            for (int r = 0; r < 4; ++r) {
                const int row = rowBase + wm * 64 + i * 16 + cq * 4 + r;
                if (OUT_BF16)
                    ((ushort*)Cv)[(size_t)row * N + col] = f2bf(acc[i][j][r]);
                else
                    ((float*)Cv)[(size_t)row * N + col] = acc[i][j][r];
            }
        }
}

// ---------------------------------------------------------------------------
// MFMA attention. grid (16, 32): qt = 15-blockIdx.x (big blocks first),
// bh = blockIdx.y. 4 waves; wave w owns queries qt*64 + w*16 .. +15.
// S = Phi_q · Phi_k^T (K=64) -> exp (no max needed, scores in (0,1]) ->
// transpose via LDS -> PV MFMA; denominator deferred to epilogue.
// Vt layout: [dim = h*64+d][b*1024 + t] bf16.  ctx out: [token][h*64+d] bf16.
// ---------------------------------------------------------------------------
__global__ __launch_bounds__(256) void attn_mfma(
    const ushort* __restrict__ Phi, const ushort* __restrict__ Vt,
    ushort* __restrict__ ctxb)
{
    const int qt = 15 - blockIdx.x;
    const int bh = blockIdx.y;
    const int b = bh >> 4, h = bh & 15;
    const int tid = threadIdx.x;
    const int lane = tid & 63;
    const int w = tid >> 6;
    const int quad = lane >> 4, m16 = lane & 15;

    __shared__ ushort K_s[4096];   // B-frag order: (nb*2+ks)*512 + lane*8
    __shared__ ushort V_s[4096];
    __shared__ ushort W_s[4096];   // A-frag order per wave: (w*2+ks)*512 + lane*8

    // Q fragments (held in registers for whole block)
    const int qrow = qt * 64 + w * 16 + m16;
    const ushort* qbase = Phi + ((size_t)bh * 1024 + qrow) * 64 + quad * 8;
    const short8 qf0 = *(const short8*)qbase;
    const short8 qf1 = *(const short8*)(qbase + 32);

    f32x4 cacc[4];
    #pragma unroll
    for (int nb = 0; nb < 4; ++nb) cacc[nb] = (f32x4)0.0f;
    float den[4] = {0.f, 0.f, 0.f, 0.f};

    // staging assignment
    const int r0 = tid >> 3;            // 0..31
    const int c8 = (tid & 7) * 8;       // feat/token offset
    const int ks_st = c8 >> 5, kc_st = (c8 >> 3) & 3;

    for (int kt = 0; kt <= qt; ++kt) {
        __syncthreads();
        #pragma unroll
        for (int i = 0; i < 2; ++i) {
            const int r = r0 + i * 32;
            const int dst = ((r >> 4) * 2 + ks_st) * 512 + (kc_st * 16 + (r & 15)) * 8;
            *(uint4*)(K_s + dst) =
                *(const uint4*)(Phi + ((size_t)bh * 1024 + kt * 64 + r) * 64 + c8);
            *(uint4*)(V_s + dst) =
                *(const uint4*)(Vt + (size_t)(h * 64 + r) * (B_SZ * T_SEQ) +
                                b * 1024 + kt * 64 + c8);
        }
        __syncthreads();

        // S = Q K^T, exp, write W_s (A-frag order), accumulate denom
        #pragma unroll
        for (int nb = 0; nb < 4; ++nb) {
            const short8 kf0 = *(const short8*)(K_s + (nb * 2 + 0) * 512 + lane * 8);
            const short8 kf1 = *(const short8*)(K_s + (nb * 2 + 1) * 512 + lane * 8);
            f32x4 s = (f32x4)0.0f;
            s = __builtin_amdgcn_mfma_f32_16x16x32_bf16(qf0, kf0, s, 0, 0, 0);
            s = __builtin_amdgcn_mfma_f32_16x16x32_bf16(qf1, kf1, s, 0, 0, 0);
            const int key = nb * 16 + m16;           // local key in tile
            const int kglob = kt * 64 + key;
            const int qg0 = qt * 64 + w * 16 + quad * 4;
            const int wbase = (w * 2 + (key >> 5)) * 512 + (((key >> 3) & 3) * 16) * 8 +
                              (quad * 4) * 8 + (key & 7);
            #pragma unroll
            for (int r = 0; r < 4; ++r) {
                float wgt = 0.0f;
                if (kglob <= qg0 + r) wgt = __expf(s[r] * 0.2f);
                den[r] += wgt;
                W_s[wbase + r * 8] = f2bf(wgt);
            }
        }
        __syncthreads();

        // PV
        const short8 wf0 = *(const short8*)(W_s + (w * 2 + 0) * 512 + lane * 8);
        const short8 wf1 = *(const short8*)(W_s + (w * 2 + 1) * 512 + lane * 8);
        #pragma unroll
        for (int nb = 0; nb < 4; ++nb) {
            const short8 vf0 = *(const short8*)(V_s + (nb * 2 + 0) * 512 + lane * 8);
            const short8 vf1 = *(const short8*)(V_s + (nb * 2 + 1) * 512 + lane * 8);
            cacc[nb] = __builtin_amdgcn_mfma_f32_16x16x32_bf16(wf0, vf0, cacc[nb], 0, 0, 0);
            cacc[nb] = __builtin_amdgcn_mfma_f32_16x16x32_bf16(wf1, vf1, cacc[nb], 0, 0, 0);
        }
    }

    // denom: sum across the 16 lanes (m16) of each quad group
    #pragma unroll
    for (int r = 0; r < 4; ++r) {
        den[r] += __shfl_xor(den[r], 1);
        den[r] += __shfl_xor(den[r], 2);
        den[r] += __shfl_xor(den[r], 4);
        den[r] += __shfl_xor(den[r], 8);
        den[r] = 1.0f / den[r];
    }

    #pragma unroll
    for (int nb = 0; nb < 4; ++nb) {
        const int dim = h * 64 + nb * 16 + m16;
        #pragma unroll
        for (int r = 0; r < 4; ++r) {
            const int token = qt * 64 + w * 16 + quad * 4 + r;
            ctxb[(size_t)(b * 1024 + token) * D_MODEL + dim] = f2bf(cacc[nb][r] * den[r]);
        }
    }
}

// ---------------------------------------------------------------------------
extern "C" void kernel_launch(void* const* d_in, const int* in_sizes, int n_in,
                              void* d_out, int out_size, void* d_ws, size_t ws_size,
                              hipStream_t stream)
{
    const float* x  = (const float*)d_in[0];
    const float* Wp = (const float*)d_in[1];
    const float* bp = (const float*)d_in[2];
    const float* Wv = (const float*)d_in[3];
    const float* Wo = (const float*)d_in[4];
    float* out = (float*)d_out;

    const int M = B_SZ * T_SEQ;  // 2048
    char* ws = (char*)d_ws;
    ushort* xb   = (ushort*)(ws);                 // 4 MB
    ushort* Wvt  = (ushort*)(ws + (4u  << 20));   // 2 MB
    ushort* Wot  = (ushort*)(ws + (6u  << 20));   // 2 MB
    ushort* Phi  = (ushort*)(ws + (8u  << 20));   // 4 MB
    ushort* Vt   = (ushort*)(ws + (12u << 20));   // 4 MB
    ushort* ctxb = (ushort*)(ws + (16u << 20));   // 4 MB

    convert_bf16<<<M * D_MODEL / (256 * 8), 256, 0, stream>>>(x, xb);
    transpose_bf16<<<dim3(32, 32), 256, 0, stream>>>(Wv, Wvt, D_MODEL, D_MODEL);
    transpose_bf16<<<dim3(32, 32), 256, 0, stream>>>(Wo, Wot, D_MODEL, D_MODEL);
    phi_kernel<<<M, 256, 0, stream>>>(x, Wp, bp, Phi);

    // Vt(1024 x 2048) = Wvt(1024x1024) x xb(2048x1024)^T  (i.e. V^T per dim)
    gemm_bf16<true><<<dim3(M / 64, D_MODEL / 128), 256, 0, stream>>>(
        Wvt, xb, Vt, D_MODEL, M, D_MODEL);
    attn_mfma<<<dim3(16, 32), 256, 0, stream>>>(Phi, Vt, ctxb);
    gemm_bf16<false><<<dim3(D_MODEL / 64, M / 128), 256, 0, stream>>>(
        ctxb, Wot, out, M, D_MODEL, D_MODEL);
}

// Round 4
// 175.561 us; speedup vs baseline: 1.9075x; 1.0752x over previous
//
#include <hip/hip_runtime.h>
#include <hip/hip_bf16.h>

#define B_SZ 2
#define T_SEQ 1024
#define D_MODEL 1024
#define N_HEADS 16
#define TREE_DEPTH 5
#define DH 64

typedef __attribute__((ext_vector_type(8))) short short8;
typedef __attribute__((ext_vector_type(4))) float f32x4;

__device__ __forceinline__ ushort f2bf(float f) {
    uint32_t u = __float_as_uint(f);
    u += 0x7FFFu + ((u >> 16) & 1u);
    return (ushort)(u >> 16);
}

// ---------------------------------------------------------------------------
// fp32 -> bf16, 8 elems/thread
// ---------------------------------------------------------------------------
__global__ __launch_bounds__(256) void convert_bf16(
    const float* __restrict__ in, ushort* __restrict__ out)
{
    const int i = (blockIdx.x * 256 + threadIdx.x) * 8;
    const float4 a = *(const float4*)(in + i);
    const float4 b = *(const float4*)(in + i + 4);
    ushort o[8] = {f2bf(a.x), f2bf(a.y), f2bf(a.z), f2bf(a.w),
                   f2bf(b.x), f2bf(b.y), f2bf(b.z), f2bf(b.w)};
    *(uint4*)(out + i) = *(const uint4*)o;
}

// ---------------------------------------------------------------------------
// W (K x N fp32) -> Wt (N x K bf16)   (square 1024x1024 use)
// ---------------------------------------------------------------------------
__global__ __launch_bounds__(256) void transpose_bf16(
    const float* __restrict__ W, ushort* __restrict__ Wt, int K, int N)
{
    __shared__ float tile[32][33];
    const int n0 = blockIdx.x * 32, k0 = blockIdx.y * 32;
    const int tx = threadIdx.x & 31, ty = threadIdx.x >> 5;
    #pragma unroll
    for (int i = 0; i < 4; ++i)
        tile[ty + i * 8][tx] = W[(size_t)(k0 + ty + i * 8) * N + n0 + tx];
    __syncthreads();
    #pragma unroll
    for (int i = 0; i < 4; ++i)
        Wt[(size_t)(n0 + ty + i * 8) * K + k0 + tx] = f2bf(tile[tx][ty + i * 8]);
}

// ---------------------------------------------------------------------------
// Wp (1024 x 80 fp32) -> Wpt (80 x 1024 bf16). grid 16 (64-k strips).
// ---------------------------------------------------------------------------
__global__ __launch_bounds__(256) void transpose_wp(
    const float* __restrict__ Wp, ushort* __restrict__ Wpt)
{
    __shared__ float tile[64 * 80];
    const int k0 = blockIdx.x * 64;
    #pragma unroll
    for (int j = 0; j < 20; ++j) {
        const int i = threadIdx.x + j * 256;          // i = k*80 + n
        tile[i] = Wp[(size_t)k0 * 80 + i];
    }
    __syncthreads();
    #pragma unroll
    for (int j = 0; j < 20; ++j) {
        const int o = threadIdx.x + j * 256;          // o = n*64 + k
        const int n = o >> 6, k = o & 63;
        Wpt[(size_t)n * 1024 + k0 + k] = f2bf(tile[k * 80 + n]);
    }
}

// ---------------------------------------------------------------------------
// paths+phi fused: P = sigmoid(xb @ Wpt^T + bp) via MFMA (wave-split K),
// then tensor-product expansion to Phi [(b*16+h)*1024+t][64] bf16.
// grid 128 (16-row tiles), 4 waves.
// ---------------------------------------------------------------------------
__global__ __launch_bounds__(256) void paths_phi(
    const ushort* __restrict__ xb, const ushort* __restrict__ Wpt,
    const float* __restrict__ bp, ushort* __restrict__ Phi)
{
    __shared__ float red[4][16][80];
    __shared__ float p_s[16][80];
    const int tid = threadIdx.x;
    const int lane = tid & 63, w = tid >> 6;
    const int quad = lane >> 4, m16 = lane & 15;
    const int row0 = blockIdx.x * 16;

    f32x4 acc[5];
    #pragma unroll
    for (int nb = 0; nb < 5; ++nb) acc[nb] = (f32x4)0.0f;

    const ushort* ap = xb + (size_t)(row0 + m16) * 1024 + w * 256 + quad * 8;
    const ushort* bpz = Wpt + (size_t)m16 * 1024 + w * 256 + quad * 8;
    #pragma unroll
    for (int it = 0; it < 8; ++it) {
        const short8 af = *(const short8*)(ap + it * 32);
        #pragma unroll
        for (int nb = 0; nb < 5; ++nb) {
            const short8 bf = *(const short8*)(bpz + (size_t)nb * 16 * 1024 + it * 32);
            acc[nb] = __builtin_amdgcn_mfma_f32_16x16x32_bf16(af, bf, acc[nb], 0, 0, 0);
        }
    }
    #pragma unroll
    for (int nb = 0; nb < 5; ++nb)
        #pragma unroll
        for (int r = 0; r < 4; ++r)
            red[w][quad * 4 + r][nb * 16 + m16] = acc[nb][r];
    __syncthreads();
    // reduce 16x80 across waves + bias + sigmoid
    #pragma unroll
    for (int j = 0; j < 5; ++j) {
        const int i = tid + j * 256;
        const int rr = i / 80, cc = i - rr * 80;
        const float v = red[0][rr][cc] + red[1][rr][cc] +
                        red[2][rr][cc] + red[3][rr][cc] + bp[cc];
        p_s[rr][cc] = 1.0f / (1.0f + __expf(-v));
    }
    __syncthreads();
    // expansion: 16 rows x 16 heads x 8 chunks(8 feats) = 2048 chunks
    #pragma unroll
    for (int j = 0; j < 8; ++j) {
        const int c = tid + j * 256;
        const int rr = c >> 7, rem = c & 127;
        const int h = rem >> 3, f8 = (rem & 7) * 8;
        const float* pr = &p_s[rr][h * 5];
        ushort o[8];
        #pragma unroll
        for (int e = 0; e < 8; ++e) {
            const int f = f8 + e;
            float val = 0.0f;
            if (f < 62) {
                int d, off;
                if (f < 2)       { d = 1; off = 0; }
                else if (f < 6)  { d = 2; off = 2; }
                else if (f < 14) { d = 3; off = 6; }
                else if (f < 30) { d = 4; off = 14; }
                else             { d = 5; off = 30; }
                const int e2 = f - off;
                float prod = 1.0f;
                for (int jj = 1; jj <= d; ++jj) {
                    const float p = pr[jj - 1];
                    prod *= ((e2 >> (d - jj)) & 1) ? (1.0f - p) : p;
                }
                val = prod;
            }
            o[e] = f2bf(val);
        }
        const int grow = row0 + rr;
        const int b = grow >> 10, t = grow & 1023;
        *(uint4*)(Phi + ((size_t)(b * 16 + h) * 1024 + t) * 64 + f8) =
            *(const uint4*)o;
    }
}

// ---------------------------------------------------------------------------
// bf16 MFMA GEMM: C(MxN) = A(MxK bf16) @ Bt(NxK bf16)^T
// BM=128, BN=64, BK=32; 4 waves. OUT_BF16 selects ushort vs float output.
// ---------------------------------------------------------------------------
template <bool OUT_BF16>
__global__ __launch_bounds__(256) void gemm_bf16(
    const ushort* __restrict__ A, const ushort* __restrict__ Bt,
    void* __restrict__ Cv, int M, int N, int K)
{
    __shared__ ushort As[128 * 32];
    __shared__ ushort Bs[64 * 32];

    const int tid = threadIdx.x;
    const int lane = tid & 63;
    const int w = tid >> 6;
    const int wm = w & 1, wn = w >> 1;
    const int rowBase = blockIdx.y * 128;
    const int colBase = blockIdx.x * 64;

    const int quad = tid & 3;
    const int arow0 = tid >> 2;
    const int brow = tid >> 2;

    const int am0 = arow0, am1 = arow0 + 64;
    const int aoff0 = (am0 >> 4) * 512 + (quad * 16 + (am0 & 15)) * 8;
    const int aoff1 = (am1 >> 4) * 512 + (quad * 16 + (am1 & 15)) * 8;
    const int boff  = (brow >> 4) * 512 + (quad * 16 + (brow & 15)) * 8;

    const ushort* Ap0 = A + (size_t)(rowBase + am0) * K + quad * 8;
    const ushort* Ap1 = A + (size_t)(rowBase + am1) * K + quad * 8;
    const ushort* Bp  = Bt + (size_t)(colBase + brow) * K + quad * 8;

    f32x4 acc[4][2];
    #pragma unroll
    for (int i = 0; i < 4; ++i) {
        acc[i][0] = (f32x4)0.0f;
        acc[i][1] = (f32x4)0.0f;
    }

    const int niter = K / 32;
    uint4 ga0 = *(const uint4*)Ap0;
    uint4 ga1 = *(const uint4*)Ap1;
    uint4 gb  = *(const uint4*)Bp;

    for (int it = 0; it < niter; ++it) {
        __syncthreads();
        *(uint4*)(As + aoff0) = ga0;
        *(uint4*)(As + aoff1) = ga1;
        *(uint4*)(Bs + boff)  = gb;
        __syncthreads();
        if (it + 1 < niter) {
            ga0 = *(const uint4*)(Ap0 + (it + 1) * 32);
            ga1 = *(const uint4*)(Ap1 + (it + 1) * 32);
            gb  = *(const uint4*)(Bp  + (it + 1) * 32);
        }
        short8 af[4], bf[2];
        #pragma unroll
        for (int j = 0; j < 4; ++j)
            af[j] = *(const short8*)(As + (wm * 4 + j) * 512 + lane * 8);
        #pragma unroll
        for (int j = 0; j < 2; ++j)
            bf[j] = *(const short8*)(Bs + (wn * 2 + j) * 512 + lane * 8);
        #pragma unroll
        for (int i = 0; i < 4; ++i)
            #pragma unroll
            for (int j = 0; j < 2; ++j)
                acc[i][j] = __builtin_amdgcn_mfma_f32_16x16x32_bf16(
                    af[i], bf[j], acc[i][j], 0, 0, 0);
    }

    const int cq = lane >> 4, cl = lane & 15;
    #pragma unroll
    for (int i = 0; i < 4; ++i)
        #pragma unroll
        for (int j = 0; j < 2; ++j) {
            const int col = colBase + wn * 32 + j * 16 + cl;
            #pragma unroll
            for (int r = 0; r < 4; ++r) {
                const int row = rowBase + wm * 64 + i * 16 + cq * 4 + r;
                if (OUT_BF16)
                    ((ushort*)Cv)[(size_t)row * N + col] = f2bf(acc[i][j][r]);
                else
                    ((float*)Cv)[(size_t)row * N + col] = acc[i][j][r];
            }
        }
}

// ---------------------------------------------------------------------------
// MFMA attention (unchanged from R3).
// ---------------------------------------------------------------------------
__global__ __launch_bounds__(256) void attn_mfma(
    const ushort* __restrict__ Phi, const ushort* __restrict__ Vt,
    ushort* __restrict__ ctxb)
{
    const int qt = 15 - blockIdx.x;
    const int bh = blockIdx.y;
    const int b = bh >> 4, h = bh & 15;
    const int tid = threadIdx.x;
    const int lane = tid & 63;
    const int w = tid >> 6;
    const int quad = lane >> 4, m16 = lane & 15;

    __shared__ ushort K_s[4096];
    __shared__ ushort V_s[4096];
    __shared__ ushort W_s[4096];

    const int qrow = qt * 64 + w * 16 + m16;
    const ushort* qbase = Phi + ((size_t)bh * 1024 + qrow) * 64 + quad * 8;
    const short8 qf0 = *(const short8*)qbase;
    const short8 qf1 = *(const short8*)(qbase + 32);

    f32x4 cacc[4];
    #pragma unroll
    for (int nb = 0; nb < 4; ++nb) cacc[nb] = (f32x4)0.0f;
    float den[4] = {0.f, 0.f, 0.f, 0.f};

    const int r0 = tid >> 3;
    const int c8 = (tid & 7) * 8;
    const int ks_st = c8 >> 5, kc_st = (c8 >> 3) & 3;

    for (int kt = 0; kt <= qt; ++kt) {
        __syncthreads();
        #pragma unroll
        for (int i = 0; i < 2; ++i) {
            const int r = r0 + i * 32;
            const int dst = ((r >> 4) * 2 + ks_st) * 512 + (kc_st * 16 + (r & 15)) * 8;
            *(uint4*)(K_s + dst) =
                *(const uint4*)(Phi + ((size_t)bh * 1024 + kt * 64 + r) * 64 + c8);
            *(uint4*)(V_s + dst) =
                *(const uint4*)(Vt + (size_t)(h * 64 + r) * (B_SZ * T_SEQ) +
                                b * 1024 + kt * 64 + c8);
        }
        __syncthreads();

        #pragma unroll
        for (int nb = 0; nb < 4; ++nb) {
            const short8 kf0 = *(const short8*)(K_s + (nb * 2 + 0) * 512 + lane * 8);
            const short8 kf1 = *(const short8*)(K_s + (nb * 2 + 1) * 512 + lane * 8);
            f32x4 s = (f32x4)0.0f;
            s = __builtin_amdgcn_mfma_f32_16x16x32_bf16(qf0, kf0, s, 0, 0, 0);
            s = __builtin_amdgcn_mfma_f32_16x16x32_bf16(qf1, kf1, s, 0, 0, 0);
            const int key = nb * 16 + m16;
            const int kglob = kt * 64 + key;
            const int qg0 = qt * 64 + w * 16 + quad * 4;
            const int wbase = (w * 2 + (key >> 5)) * 512 + (((key >> 3) & 3) * 16) * 8 +
                              (quad * 4) * 8 + (key & 7);
            #pragma unroll
            for (int r = 0; r < 4; ++r) {
                float wgt = 0.0f;
                if (kglob <= qg0 + r) wgt = __expf(s[r] * 0.2f);
                den[r] += wgt;
                W_s[wbase + r * 8] = f2bf(wgt);
            }
        }
        __syncthreads();

        const short8 wf0 = *(const short8*)(W_s + (w * 2 + 0) * 512 + lane * 8);
        const short8 wf1 = *(const short8*)(W_s + (w * 2 + 1) * 512 + lane * 8);
        #pragma unroll
        for (int nb = 0; nb < 4; ++nb) {
            const short8 vf0 = *(const short8*)(V_s + (nb * 2 + 0) * 512 + lane * 8);
            const short8 vf1 = *(const short8*)(V_s + (nb * 2 + 1) * 512 + lane * 8);
            cacc[nb] = __builtin_amdgcn_mfma_f32_16x16x32_bf16(wf0, vf0, cacc[nb], 0, 0, 0);
            cacc[nb] = __builtin_amdgcn_mfma_f32_16x16x32_bf16(wf1, vf1, cacc[nb], 0, 0, 0);
        }
    }

    #pragma unroll
    for (int r = 0; r < 4; ++r) {
        den[r] += __shfl_xor(den[r], 1);
        den[r] += __shfl_xor(den[r], 2);
        den[r] += __shfl_xor(den[r], 4);
        den[r] += __shfl_xor(den[r], 8);
        den[r] = 1.0f / den[r];
    }

    #pragma unroll
    for (int nb = 0; nb < 4; ++nb) {
        const int dim = h * 64 + nb * 16 + m16;
        #pragma unroll
        for (int r = 0; r < 4; ++r) {
            const int token = qt * 64 + w * 16 + quad * 4 + r;
            ctxb[(size_t)(b * 1024 + token) * D_MODEL + dim] = f2bf(cacc[nb][r] * den[r]);
        }
    }
}

// ---------------------------------------------------------------------------
extern "C" void kernel_launch(void* const* d_in, const int* in_sizes, int n_in,
                              void* d_out, int out_size, void* d_ws, size_t ws_size,
                              hipStream_t stream)
{
    const float* x  = (const float*)d_in[0];
    const float* Wp = (const float*)d_in[1];
    const float* bp = (const float*)d_in[2];
    const float* Wv = (const float*)d_in[3];
    const float* Wo = (const float*)d_in[4];
    float* out = (float*)d_out;

    const int M = B_SZ * T_SEQ;  // 2048
    char* ws = (char*)d_ws;
    ushort* xb   = (ushort*)(ws);                 // 4 MB
    ushort* Wvt  = (ushort*)(ws + (4u  << 20));   // 2 MB
    ushort* Wot  = (ushort*)(ws + (6u  << 20));   // 2 MB
    ushort* Phi  = (ushort*)(ws + (8u  << 20));   // 4 MB
    ushort* Vt   = (ushort*)(ws + (12u << 20));   // 4 MB
    ushort* ctxb = (ushort*)(ws + (16u << 20));   // 4 MB
    ushort* Wpt  = (ushort*)(ws + (20u << 20));   // 160 KB

    convert_bf16<<<M * D_MODEL / (256 * 8), 256, 0, stream>>>(x, xb);
    transpose_wp<<<16, 256, 0, stream>>>(Wp, Wpt);
    transpose_bf16<<<dim3(32, 32), 256, 0, stream>>>(Wv, Wvt, D_MODEL, D_MODEL);
    transpose_bf16<<<dim3(32, 32), 256, 0, stream>>>(Wo, Wot, D_MODEL, D_MODEL);
    paths_phi<<<128, 256, 0, stream>>>(xb, Wpt, bp, Phi);

    // Vt(1024 x 2048) = Wvt(1024x1024) x xb(2048x1024)^T
    gemm_bf16<true><<<dim3(M / 64, D_MODEL / 128), 256, 0, stream>>>(
        Wvt, xb, Vt, D_MODEL, M, D_MODEL);
    attn_mfma<<<dim3(16, 32), 256, 0, stream>>>(Phi, Vt, ctxb);
    gemm_bf16<false><<<dim3(D_MODEL / 64, M / 128), 256, 0, stream>>>(
        ctxb, Wot, out, M, D_MODEL, D_MODEL);
}

// Round 5
// 160.113 us; speedup vs baseline: 2.0915x; 1.0965x over previous
//
#include <hip/hip_runtime.h>
#include <hip/hip_bf16.h>

#define B_SZ 2
#define T_SEQ 1024
#define D_MODEL 1024
#define N_HEADS 16
#define TREE_DEPTH 5
#define DH 64

typedef __attribute__((ext_vector_type(8))) short short8;
typedef __attribute__((ext_vector_type(4))) float f32x4;

__device__ __forceinline__ ushort f2bf(float f) {
    uint32_t u = __float_as_uint(f);
    u += 0x7FFFu + ((u >> 16) & 1u);
    return (ushort)(u >> 16);
}

// async global->LDS 16B/lane; dest = wave-uniform base + lane*16
__device__ __forceinline__ void gll16(const void* g, void* l) {
    __builtin_amdgcn_global_load_lds(
        (const __attribute__((address_space(1))) void*)g,
        (__attribute__((address_space(3))) void*)l, 16, 0, 0);
}

// ---------------------------------------------------------------------------
// Fused prologue: [0,1024) convert x->xb ; [1024,3072) transpose Wv/Wo ;
// [3072,3088) transpose Wp.
// ---------------------------------------------------------------------------
__global__ __launch_bounds__(256) void prologue(
    const float* __restrict__ x, const float* __restrict__ Wv,
    const float* __restrict__ Wo, const float* __restrict__ Wp,
    ushort* __restrict__ xb, ushort* __restrict__ Wvt,
    ushort* __restrict__ Wot, ushort* __restrict__ Wpt)
{
    __shared__ __align__(16) char sm[20480];
    const int bid = blockIdx.x, tid = threadIdx.x;
    if (bid < 1024) {
        const int i = (bid * 256 + tid) * 8;
        const float4 a = *(const float4*)(x + i);
        const float4 b = *(const float4*)(x + i + 4);
        ushort o[8] = {f2bf(a.x), f2bf(a.y), f2bf(a.z), f2bf(a.w),
                       f2bf(b.x), f2bf(b.y), f2bf(b.z), f2bf(b.w)};
        *(uint4*)(xb + i) = *(const uint4*)o;
    } else if (bid < 3072) {
        const int t = bid - 1024;
        const float* W = (t < 1024) ? Wv : Wo;
        ushort* Wt = (t < 1024) ? Wvt : Wot;
        const int ti = t & 1023;
        const int n0 = (ti & 31) * 32, k0 = (ti >> 5) * 32;
        float (*tile)[33] = (float(*)[33])sm;
        const int tx = tid & 31, ty = tid >> 5;
        #pragma unroll
        for (int i = 0; i < 4; ++i)
            tile[ty + i * 8][tx] = W[(size_t)(k0 + ty + i * 8) * 1024 + n0 + tx];
        __syncthreads();
        #pragma unroll
        for (int i = 0; i < 4; ++i)
            Wt[(size_t)(n0 + ty + i * 8) * 1024 + k0 + tx] = f2bf(tile[tx][ty + i * 8]);
    } else {
        float* tile = (float*)sm;            // 64*80
        const int k0 = (bid - 3072) * 64;
        #pragma unroll
        for (int j = 0; j < 20; ++j) {
            const int i = tid + j * 256;     // i = k*80 + n
            tile[i] = Wp[(size_t)k0 * 80 + i];
        }
        __syncthreads();
        #pragma unroll
        for (int j = 0; j < 20; ++j) {
            const int o = tid + j * 256;     // o = n*64 + k
            const int n = o >> 6, k = o & 63;
            Wpt[(size_t)n * 1024 + k0 + k] = f2bf(tile[k * 80 + n]);
        }
    }
}

// ---------------------------------------------------------------------------
// bf16 MFMA GEMM body: C(MxN) = A(MxK) @ Bt(NxK)^T. BM=128 BN=64 BK=32,
// 4 waves. Staging via global_load_lds: wave w stages A sub-blocks {2w,2w+1}
// and B sub-block {w}; lane l loads row (l&15), kchunk (l>>4)*8 so the
// implicit dest (base + l*16B) IS the MFMA fragment order.
// ---------------------------------------------------------------------------
template <bool OUT_BF16>
__device__ __forceinline__ void gemm_body(
    const ushort* __restrict__ A, const ushort* __restrict__ Bt,
    void* __restrict__ Cv, int N, int K, int bx, int by,
    ushort* As, ushort* Bs)
{
    const int tid = threadIdx.x;
    const int lane = tid & 63;
    const int w = tid >> 6;
    const int wm = w & 1, wn = w >> 1;
    const int rowBase = by * 128;
    const int colBase = bx * 64;

    const int srow = lane & 15;
    const int sk = (lane >> 4) * 8;

    const ushort* gA0 = A + (size_t)(rowBase + 2 * w * 16 + srow) * K + sk;
    const ushort* gA1 = gA0 + (size_t)16 * K;
    const ushort* gB  = Bt + (size_t)(colBase + w * 16 + srow) * K + sk;
    ushort* dA0 = As + (2 * w) * 512;
    ushort* dA1 = As + (2 * w + 1) * 512;
    ushort* dB  = Bs + w * 512;

    f32x4 acc[4][2];
    #pragma unroll
    for (int i = 0; i < 4; ++i) {
        acc[i][0] = (f32x4)0.0f;
        acc[i][1] = (f32x4)0.0f;
    }

    for (int it = 0; it < K / 32; ++it) {
        __syncthreads();                    // prior compute done reading LDS
        gll16(gA0 + it * 32, dA0);
        gll16(gA1 + it * 32, dA1);
        gll16(gB  + it * 32, dB);
        __syncthreads();                    // compiler drains vmcnt before barrier
        short8 af[4], bf[2];
        #pragma unroll
        for (int j = 0; j < 4; ++j)
            af[j] = *(const short8*)(As + (wm * 4 + j) * 512 + lane * 8);
        #pragma unroll
        for (int j = 0; j < 2; ++j)
            bf[j] = *(const short8*)(Bs + (wn * 2 + j) * 512 + lane * 8);
        #pragma unroll
        for (int i = 0; i < 4; ++i)
            #pragma unroll
            for (int j = 0; j < 2; ++j)
                acc[i][j] = __builtin_amdgcn_mfma_f32_16x16x32_bf16(
                    af[i], bf[j], acc[i][j], 0, 0, 0);
    }

    const int cq = lane >> 4, cl = lane & 15;
    #pragma unroll
    for (int i = 0; i < 4; ++i)
        #pragma unroll
        for (int j = 0; j < 2; ++j) {
            const int col = colBase + wn * 32 + j * 16 + cl;
            #pragma unroll
            for (int r = 0; r < 4; ++r) {
                const int row = rowBase + wm * 64 + i * 16 + cq * 4 + r;
                if (OUT_BF16)
                    ((ushort*)Cv)[(size_t)row * N + col] = f2bf(acc[i][j][r]);
                else
                    ((float*)Cv)[(size_t)row * N + col] = acc[i][j][r];
            }
        }
}

// ---------------------------------------------------------------------------
// paths+phi body (MFMA paths GEMM wave-split over K + feature expansion)
// ---------------------------------------------------------------------------
__device__ __forceinline__ void phi_body(
    const ushort* __restrict__ xb, const ushort* __restrict__ Wpt,
    const float* __restrict__ bp, ushort* __restrict__ Phi,
    int blk, float* red, float* p_s)
{
    const int tid = threadIdx.x;
    const int lane = tid & 63, w = tid >> 6;
    const int quad = lane >> 4, m16 = lane & 15;
    const int row0 = blk * 16;

    f32x4 acc[5];
    #pragma unroll
    for (int nb = 0; nb < 5; ++nb) acc[nb] = (f32x4)0.0f;

    const ushort* ap = xb + (size_t)(row0 + m16) * 1024 + w * 256 + quad * 8;
    const ushort* bpz = Wpt + (size_t)m16 * 1024 + w * 256 + quad * 8;
    #pragma unroll
    for (int it = 0; it < 8; ++it) {
        const short8 af = *(const short8*)(ap + it * 32);
        #pragma unroll
        for (int nb = 0; nb < 5; ++nb) {
            const short8 bf = *(const short8*)(bpz + (size_t)nb * 16 * 1024 + it * 32);
            acc[nb] = __builtin_amdgcn_mfma_f32_16x16x32_bf16(af, bf, acc[nb], 0, 0, 0);
        }
    }
    #pragma unroll
    for (int nb = 0; nb < 5; ++nb)
        #pragma unroll
        for (int r = 0; r < 4; ++r)
            red[(w * 16 + quad * 4 + r) * 80 + nb * 16 + m16] = acc[nb][r];
    __syncthreads();
    #pragma unroll
    for (int j = 0; j < 5; ++j) {
        const int i = tid + j * 256;
        const int rr = i / 80, cc = i - rr * 80;
        const float v = red[(0 * 16 + rr) * 80 + cc] + red[(1 * 16 + rr) * 80 + cc] +
                        red[(2 * 16 + rr) * 80 + cc] + red[(3 * 16 + rr) * 80 + cc] + bp[cc];
        p_s[rr * 80 + cc] = 1.0f / (1.0f + __expf(-v));
    }
    __syncthreads();
    #pragma unroll
    for (int j = 0; j < 8; ++j) {
        const int c = tid + j * 256;
        const int rr = c >> 7, rem = c & 127;
        const int h = rem >> 3, f8 = (rem & 7) * 8;
        const float* pr = &p_s[rr * 80 + h * 5];
        ushort o[8];
        #pragma unroll
        for (int e = 0; e < 8; ++e) {
            const int f = f8 + e;
            float val = 0.0f;
            if (f < 62) {
                int d, off;
                if (f < 2)       { d = 1; off = 0; }
                else if (f < 6)  { d = 2; off = 2; }
                else if (f < 14) { d = 3; off = 6; }
                else if (f < 30) { d = 4; off = 14; }
                else             { d = 5; off = 30; }
                const int e2 = f - off;
                float prod = 1.0f;
                for (int jj = 1; jj <= d; ++jj) {
                    const float p = pr[jj - 1];
                    prod *= ((e2 >> (d - jj)) & 1) ? (1.0f - p) : p;
                }
                val = prod;
            }
            o[e] = f2bf(val);
        }
        const int grow = row0 + rr;
        const int b = grow >> 10, t = grow & 1023;
        *(uint4*)(Phi + ((size_t)(b * 16 + h) * 1024 + t) * 64 + f8) =
            *(const uint4*)o;
    }
}

// ---------------------------------------------------------------------------
// mid: blocks [0,256) = Vt GEMM (Wvt @ xb^T), blocks [256,384) = paths+phi
// ---------------------------------------------------------------------------
__global__ __launch_bounds__(256) void mid_kernel(
    const ushort* __restrict__ xb, const ushort* __restrict__ Wvt,
    const ushort* __restrict__ Wpt, const float* __restrict__ bp,
    ushort* __restrict__ Vt, ushort* __restrict__ Phi)
{
    __shared__ __align__(16) char sm[25600];
    if (blockIdx.x < 256) {
        ushort* As = (ushort*)sm;
        ushort* Bs = As + 128 * 32;
        gemm_body<true>(Wvt, xb, Vt, 2048, 1024,
                        blockIdx.x & 31, blockIdx.x >> 5, As, Bs);
    } else {
        float* red = (float*)sm;             // 4*16*80
        float* p_s = (float*)(sm + 20480);   // 16*80
        phi_body(xb, Wpt, bp, Phi, blockIdx.x - 256, red, p_s);
    }
}

// ---------------------------------------------------------------------------
// final GEMM: out = ctxb @ Wot^T  (fp32 out)
// ---------------------------------------------------------------------------
__global__ __launch_bounds__(256) void gemm_out(
    const ushort* __restrict__ ctxb, const ushort* __restrict__ Wot,
    float* __restrict__ out)
{
    __shared__ __align__(16) ushort sm[128 * 32 + 64 * 32];
    gemm_body<false>(ctxb, Wot, out, 1024, 1024,
                     blockIdx.x, blockIdx.y, sm, sm + 128 * 32);
}

// ---------------------------------------------------------------------------
// MFMA attention (unchanged from R3/R4)
// ---------------------------------------------------------------------------
__global__ __launch_bounds__(256) void attn_mfma(
    const ushort* __restrict__ Phi, const ushort* __restrict__ Vt,
    ushort* __restrict__ ctxb)
{
    const int qt = 15 - blockIdx.x;
    const int bh = blockIdx.y;
    const int b = bh >> 4, h = bh & 15;
    const int tid = threadIdx.x;
    const int lane = tid & 63;
    const int w = tid >> 6;
    const int quad = lane >> 4, m16 = lane & 15;

    __shared__ ushort K_s[4096];
    __shared__ ushort V_s[4096];
    __shared__ ushort W_s[4096];

    const int qrow = qt * 64 + w * 16 + m16;
    const ushort* qbase = Phi + ((size_t)bh * 1024 + qrow) * 64 + quad * 8;
    const short8 qf0 = *(const short8*)qbase;
    const short8 qf1 = *(const short8*)(qbase + 32);

    f32x4 cacc[4];
    #pragma unroll
    for (int nb = 0; nb < 4; ++nb) cacc[nb] = (f32x4)0.0f;
    float den[4] = {0.f, 0.f, 0.f, 0.f};

    const int r0 = tid >> 3;
    const int c8 = (tid & 7) * 8;
    const int ks_st = c8 >> 5, kc_st = (c8 >> 3) & 3;

    for (int kt = 0; kt <= qt; ++kt) {
        __syncthreads();
        #pragma unroll
        for (int i = 0; i < 2; ++i) {
            const int r = r0 + i * 32;
            const int dst = ((r >> 4) * 2 + ks_st) * 512 + (kc_st * 16 + (r & 15)) * 8;
            *(uint4*)(K_s + dst) =
                *(const uint4*)(Phi + ((size_t)bh * 1024 + kt * 64 + r) * 64 + c8);
            *(uint4*)(V_s + dst) =
                *(const uint4*)(Vt + (size_t)(h * 64 + r) * (B_SZ * T_SEQ) +
                                b * 1024 + kt * 64 + c8);
        }
        __syncthreads();

        #pragma unroll
        for (int nb = 0; nb < 4; ++nb) {
            const short8 kf0 = *(const short8*)(K_s + (nb * 2 + 0) * 512 + lane * 8);
            const short8 kf1 = *(const short8*)(K_s + (nb * 2 + 1) * 512 + lane * 8);
            f32x4 s = (f32x4)0.0f;
            s = __builtin_amdgcn_mfma_f32_16x16x32_bf16(qf0, kf0, s, 0, 0, 0);
            s = __builtin_amdgcn_mfma_f32_16x16x32_bf16(qf1, kf1, s, 0, 0, 0);
            const int key = nb * 16 + m16;
            const int kglob = kt * 64 + key;
            const int qg0 = qt * 64 + w * 16 + quad * 4;
            const int wbase = (w * 2 + (key >> 5)) * 512 + (((key >> 3) & 3) * 16) * 8 +
                              (quad * 4) * 8 + (key & 7);
            #pragma unroll
            for (int r = 0; r < 4; ++r) {
                float wgt = 0.0f;
                if (kglob <= qg0 + r) wgt = __expf(s[r] * 0.2f);
                den[r] += wgt;
                W_s[wbase + r * 8] = f2bf(wgt);
            }
        }
        __syncthreads();

        const short8 wf0 = *(const short8*)(W_s + (w * 2 + 0) * 512 + lane * 8);
        const short8 wf1 = *(const short8*)(W_s + (w * 2 + 1) * 512 + lane * 8);
        #pragma unroll
        for (int nb = 0; nb < 4; ++nb) {
            const short8 vf0 = *(const short8*)(V_s + (nb * 2 + 0) * 512 + lane * 8);
            const short8 vf1 = *(const short8*)(V_s + (nb * 2 + 1) * 512 + lane * 8);
            cacc[nb] = __builtin_amdgcn_mfma_f32_16x16x32_bf16(wf0, vf0, cacc[nb], 0, 0, 0);
            cacc[nb] = __builtin_amdgcn_mfma_f32_16x16x32_bf16(wf1, vf1, cacc[nb], 0, 0, 0);
        }
    }

    #pragma unroll
    for (int r = 0; r < 4; ++r) {
        den[r] += __shfl_xor(den[r], 1);
        den[r] += __shfl_xor(den[r], 2);
        den[r] += __shfl_xor(den[r], 4);
        den[r] += __shfl_xor(den[r], 8);
        den[r] = 1.0f / den[r];
    }

    #pragma unroll
    for (int nb = 0; nb < 4; ++nb) {
        const int dim = h * 64 + nb * 16 + m16;
        #pragma unroll
        for (int r = 0; r < 4; ++r) {
            const int token = qt * 64 + w * 16 + quad * 4 + r;
            ctxb[(size_t)(b * 1024 + token) * D_MODEL + dim] = f2bf(cacc[nb][r] * den[r]);
        }
    }
}

// ---------------------------------------------------------------------------
extern "C" void kernel_launch(void* const* d_in, const int* in_sizes, int n_in,
                              void* d_out, int out_size, void* d_ws, size_t ws_size,
                              hipStream_t stream)
{
    const float* x  = (const float*)d_in[0];
    const float* Wp = (const float*)d_in[1];
    const float* bp = (const float*)d_in[2];
    const float* Wv = (const float*)d_in[3];
    const float* Wo = (const float*)d_in[4];
    float* out = (float*)d_out;

    char* ws = (char*)d_ws;
    ushort* xb   = (ushort*)(ws);                 // 4 MB
    ushort* Wvt  = (ushort*)(ws + (4u  << 20));   // 2 MB
    ushort* Wot  = (ushort*)(ws + (6u  << 20));   // 2 MB
    ushort* Phi  = (ushort*)(ws + (8u  << 20));   // 4 MB
    ushort* Vt   = (ushort*)(ws + (12u << 20));   // 4 MB
    ushort* ctxb = (ushort*)(ws + (16u << 20));   // 4 MB
    ushort* Wpt  = (ushort*)(ws + (20u << 20));   // 160 KB

    prologue<<<3088, 256, 0, stream>>>(x, Wv, Wo, Wp, xb, Wvt, Wot, Wpt);
    mid_kernel<<<384, 256, 0, stream>>>(xb, Wvt, Wpt, bp, Vt, Phi);
    attn_mfma<<<dim3(16, 32), 256, 0, stream>>>(Phi, Vt, ctxb);
    gemm_out<<<dim3(16, 16), 256, 0, stream>>>(ctxb, Wot, out);
}

// Round 6
// 151.523 us; speedup vs baseline: 2.2101x; 1.0567x over previous
//
#include <hip/hip_runtime.h>
#include <hip/hip_bf16.h>

#define B_SZ 2
#define T_SEQ 1024
#define D_MODEL 1024
#define N_HEADS 16
#define TREE_DEPTH 5
#define DH 64

typedef __attribute__((ext_vector_type(8))) short short8;
typedef __attribute__((ext_vector_type(4))) float f32x4;

__device__ __forceinline__ ushort f2bf(float f) {
    uint32_t u = __float_as_uint(f);
    u += 0x7FFFu + ((u >> 16) & 1u);
    return (ushort)(u >> 16);
}

// async global->LDS 16B/lane; dest = wave-uniform base + lane*16
__device__ __forceinline__ void gll16(const void* g, void* l) {
    __builtin_amdgcn_global_load_lds(
        (const __attribute__((address_space(1))) void*)g,
        (__attribute__((address_space(3))) void*)l, 16, 0, 0);
}

// ---------------------------------------------------------------------------
// Fused prologue: [0,1024) convert x->xb ; [1024,3072) transpose Wv/Wo ;
// [3072,3088) transpose Wp.
// ---------------------------------------------------------------------------
__global__ __launch_bounds__(256) void prologue(
    const float* __restrict__ x, const float* __restrict__ Wv,
    const float* __restrict__ Wo, const float* __restrict__ Wp,
    ushort* __restrict__ xb, ushort* __restrict__ Wvt,
    ushort* __restrict__ Wot, ushort* __restrict__ Wpt)
{
    __shared__ __align__(16) char sm[20480];
    const int bid = blockIdx.x, tid = threadIdx.x;
    if (bid < 1024) {
        const int i = (bid * 256 + tid) * 8;
        const float4 a = *(const float4*)(x + i);
        const float4 b = *(const float4*)(x + i + 4);
        ushort o[8] = {f2bf(a.x), f2bf(a.y), f2bf(a.z), f2bf(a.w),
                       f2bf(b.x), f2bf(b.y), f2bf(b.z), f2bf(b.w)};
        *(uint4*)(xb + i) = *(const uint4*)o;
    } else if (bid < 3072) {
        const int t = bid - 1024;
        const float* W = (t < 1024) ? Wv : Wo;
        ushort* Wt = (t < 1024) ? Wvt : Wot;
        const int ti = t & 1023;
        const int n0 = (ti & 31) * 32, k0 = (ti >> 5) * 32;
        float (*tile)[33] = (float(*)[33])sm;
        const int tx = tid & 31, ty = tid >> 5;
        #pragma unroll
        for (int i = 0; i < 4; ++i)
            tile[ty + i * 8][tx] = W[(size_t)(k0 + ty + i * 8) * 1024 + n0 + tx];
        __syncthreads();
        #pragma unroll
        for (int i = 0; i < 4; ++i)
            Wt[(size_t)(n0 + ty + i * 8) * 1024 + k0 + tx] = f2bf(tile[tx][ty + i * 8]);
    } else {
        float* tile = (float*)sm;            // 64*80
        const int k0 = (bid - 3072) * 64;
        #pragma unroll
        for (int j = 0; j < 20; ++j) {
            const int i = tid + j * 256;     // i = k*80 + n
            tile[i] = Wp[(size_t)k0 * 80 + i];
        }
        __syncthreads();
        #pragma unroll
        for (int j = 0; j < 20; ++j) {
            const int o = tid + j * 256;     // o = n*64 + k
            const int n = o >> 6, k = o & 63;
            Wpt[(size_t)n * 1024 + k0 + k] = f2bf(tile[k * 80 + n]);
        }
    }
}

// ---------------------------------------------------------------------------
// bf16 MFMA GEMM body: C(MxN) = A(MxK) @ Bt(NxK)^T. BM=64 BN=64 BK=64,
// 4 waves (2x2, each 32x32), double-buffered gll16 staging, 1 barrier/iter.
// As/Bs each hold 2 buffers of 4096 ushorts; sub-block (rb*2+ks)*512,
// lane l -> row (l&15), k-chunk (l>>4)*8 (A-frag order).
// ---------------------------------------------------------------------------
template <bool OUT_BF16>
__device__ __forceinline__ void gemm_body(
    const ushort* __restrict__ A, const ushort* __restrict__ Bt,
    void* __restrict__ Cv, int N, int K, int bx, int by,
    ushort* As, ushort* Bs)
{
    const int tid = threadIdx.x;
    const int lane = tid & 63;
    const int w = tid >> 6;
    const int wm = w & 1, wn = w >> 1;
    const int rowBase = by * 64;
    const int colBase = bx * 64;

    const int srow = lane & 15;
    const int sk = (lane >> 4) * 8;

    const ushort* gA = A + (size_t)(rowBase + w * 16 + srow) * K + sk;
    const ushort* gB = Bt + (size_t)(colBase + w * 16 + srow) * K + sk;

    f32x4 acc[2][2];
    #pragma unroll
    for (int i = 0; i < 2; ++i) {
        acc[i][0] = (f32x4)0.0f;
        acc[i][1] = (f32x4)0.0f;
    }

    // preload tile 0
    gll16(gA,      As + (w * 2 + 0) * 512);
    gll16(gA + 32, As + (w * 2 + 1) * 512);
    gll16(gB,      Bs + (w * 2 + 0) * 512);
    gll16(gB + 32, Bs + (w * 2 + 1) * 512);

    const int niter = K / 64;
    for (int it = 0; it < niter; ++it) {
        __syncthreads();                 // drains this tile's loads; prev reads done
        const int cur = (it & 1) * 4096;
        if (it + 1 < niter) {
            const int nxt = ((it + 1) & 1) * 4096;
            const int ko = (it + 1) * 64;
            gll16(gA + ko,      As + nxt + (w * 2 + 0) * 512);
            gll16(gA + ko + 32, As + nxt + (w * 2 + 1) * 512);
            gll16(gB + ko,      Bs + nxt + (w * 2 + 0) * 512);
            gll16(gB + ko + 32, Bs + nxt + (w * 2 + 1) * 512);
        }
        #pragma unroll
        for (int ks = 0; ks < 2; ++ks) {
            short8 af[2], bf[2];
            #pragma unroll
            for (int i = 0; i < 2; ++i)
                af[i] = *(const short8*)(As + cur + ((wm * 2 + i) * 2 + ks) * 512 + lane * 8);
            #pragma unroll
            for (int j = 0; j < 2; ++j)
                bf[j] = *(const short8*)(Bs + cur + ((wn * 2 + j) * 2 + ks) * 512 + lane * 8);
            #pragma unroll
            for (int i = 0; i < 2; ++i)
                #pragma unroll
                for (int j = 0; j < 2; ++j)
                    acc[i][j] = __builtin_amdgcn_mfma_f32_16x16x32_bf16(
                        af[i], bf[j], acc[i][j], 0, 0, 0);
        }
    }

    const int quad = lane >> 4, m16 = lane & 15;
    #pragma unroll
    for (int i = 0; i < 2; ++i)
        #pragma unroll
        for (int j = 0; j < 2; ++j) {
            const int col = colBase + wn * 32 + j * 16 + m16;
            #pragma unroll
            for (int r = 0; r < 4; ++r) {
                const int row = rowBase + wm * 32 + i * 16 + quad * 4 + r;
                if (OUT_BF16)
                    ((ushort*)Cv)[(size_t)row * N + col] = f2bf(acc[i][j][r]);
                else
                    ((float*)Cv)[(size_t)row * N + col] = acc[i][j][r];
            }
        }
}

// ---------------------------------------------------------------------------
// paths+phi body (unchanged from R5)
// ---------------------------------------------------------------------------
__device__ __forceinline__ void phi_body(
    const ushort* __restrict__ xb, const ushort* __restrict__ Wpt,
    const float* __restrict__ bp, ushort* __restrict__ Phi,
    int blk, float* red, float* p_s)
{
    const int tid = threadIdx.x;
    const int lane = tid & 63, w = tid >> 6;
    const int quad = lane >> 4, m16 = lane & 15;
    const int row0 = blk * 16;

    f32x4 acc[5];
    #pragma unroll
    for (int nb = 0; nb < 5; ++nb) acc[nb] = (f32x4)0.0f;

    const ushort* ap = xb + (size_t)(row0 + m16) * 1024 + w * 256 + quad * 8;
    const ushort* bpz = Wpt + (size_t)m16 * 1024 + w * 256 + quad * 8;
    #pragma unroll
    for (int it = 0; it < 8; ++it) {
        const short8 af = *(const short8*)(ap + it * 32);
        #pragma unroll
        for (int nb = 0; nb < 5; ++nb) {
            const short8 bf = *(const short8*)(bpz + (size_t)nb * 16 * 1024 + it * 32);
            acc[nb] = __builtin_amdgcn_mfma_f32_16x16x32_bf16(af, bf, acc[nb], 0, 0, 0);
        }
    }
    #pragma unroll
    for (int nb = 0; nb < 5; ++nb)
        #pragma unroll
        for (int r = 0; r < 4; ++r)
            red[(w * 16 + quad * 4 + r) * 80 + nb * 16 + m16] = acc[nb][r];
    __syncthreads();
    #pragma unroll
    for (int j = 0; j < 5; ++j) {
        const int i = tid + j * 256;
        const int rr = i / 80, cc = i - rr * 80;
        const float v = red[(0 * 16 + rr) * 80 + cc] + red[(1 * 16 + rr) * 80 + cc] +
                        red[(2 * 16 + rr) * 80 + cc] + red[(3 * 16 + rr) * 80 + cc] + bp[cc];
        p_s[rr * 80 + cc] = 1.0f / (1.0f + __expf(-v));
    }
    __syncthreads();
    #pragma unroll
    for (int j = 0; j < 8; ++j) {
        const int c = tid + j * 256;
        const int rr = c >> 7, rem = c & 127;
        const int h = rem >> 3, f8 = (rem & 7) * 8;
        const float* pr = &p_s[rr * 80 + h * 5];
        ushort o[8];
        #pragma unroll
        for (int e = 0; e < 8; ++e) {
            const int f = f8 + e;
            float val = 0.0f;
            if (f < 62) {
                int d, off;
                if (f < 2)       { d = 1; off = 0; }
                else if (f < 6)  { d = 2; off = 2; }
                else if (f < 14) { d = 3; off = 6; }
                else if (f < 30) { d = 4; off = 14; }
                else             { d = 5; off = 30; }
                const int e2 = f - off;
                float prod = 1.0f;
                for (int jj = 1; jj <= d; ++jj) {
                    const float p = pr[jj - 1];
                    prod *= ((e2 >> (d - jj)) & 1) ? (1.0f - p) : p;
                }
                val = prod;
            }
            o[e] = f2bf(val);
        }
        const int grow = row0 + rr;
        const int b = grow >> 10, t = grow & 1023;
        *(uint4*)(Phi + ((size_t)(b * 16 + h) * 1024 + t) * 64 + f8) =
            *(const uint4*)o;
    }
}

// ---------------------------------------------------------------------------
// mid: blocks [0,512) = Vt GEMM (Wvt @ xb^T), blocks [512,640) = paths+phi
// ---------------------------------------------------------------------------
__global__ __launch_bounds__(256) void mid_kernel(
    const ushort* __restrict__ xb, const ushort* __restrict__ Wvt,
    const ushort* __restrict__ Wpt, const float* __restrict__ bp,
    ushort* __restrict__ Vt, ushort* __restrict__ Phi)
{
    __shared__ __align__(16) char sm[32768];
    if (blockIdx.x < 512) {
        ushort* As = (ushort*)sm;           // 2 x 4096
        ushort* Bs = As + 8192;             // 2 x 4096
        gemm_body<true>(Wvt, xb, Vt, 2048, 1024,
                        blockIdx.x & 31, blockIdx.x >> 5, As, Bs);
    } else {
        float* red = (float*)sm;             // 4*16*80
        float* p_s = (float*)(sm + 20480);   // 16*80
        phi_body(xb, Wpt, bp, Phi, blockIdx.x - 512, red, p_s);
    }
}

// ---------------------------------------------------------------------------
// final GEMM: out = ctxb @ Wot^T  (fp32 out). grid (16, 32).
// ---------------------------------------------------------------------------
__global__ __launch_bounds__(256) void gemm_out(
    const ushort* __restrict__ ctxb, const ushort* __restrict__ Wot,
    float* __restrict__ out)
{
    __shared__ __align__(16) ushort sm[16384];
    gemm_body<false>(ctxb, Wot, out, 1024, 1024,
                     blockIdx.x, blockIdx.y, sm, sm + 8192);
}

// ---------------------------------------------------------------------------
// MFMA attention, S^T form. grid (16, 32): qt = 15-bx, bh = by.
// Wave w owns queries qt*64+w*16..+15 (held as B-operand frags in regs).
// S^T = mfma(K, Q): lane holds (query m16, keys quad*4+r) -> weights pack
// into one ds_write_b64 in PV A-frag order. K/V double-buffered via gll16.
// ---------------------------------------------------------------------------
__global__ __launch_bounds__(256) void attn_mfma(
    const ushort* __restrict__ Phi, const ushort* __restrict__ Vt,
    ushort* __restrict__ ctxb)
{
    const int qt = 15 - blockIdx.x;
    const int bh = blockIdx.y;
    const int b = bh >> 4, h = bh & 15;
    const int tid = threadIdx.x;
    const int lane = tid & 63;
    const int w = tid >> 6;
    const int quad = lane >> 4, m16 = lane & 15;

    __shared__ __align__(16) ushort K_s[2][4096];
    __shared__ __align__(16) ushort V_s[2][4096];
    __shared__ __align__(16) ushort W_s[4096];
    __shared__ float den_s[4][16];

    const int srow = lane & 15;
    const int sk = (lane >> 4) * 8;
    const ushort* gK = Phi + (size_t)bh * 1024 * 64 + (w * 16 + srow) * 64 + sk;
    const ushort* gV = Vt + (size_t)(h * 64 + w * 16 + srow) * 2048 + b * 1024 + sk;

    // Q fragments (B operand): lane holds query row m16, feats quad*8
    const int qglob = qt * 64 + w * 16 + m16;
    const ushort* qbase = Phi + ((size_t)bh * 1024 + qglob) * 64 + quad * 8;
    const short8 qf0 = *(const short8*)qbase;
    const short8 qf1 = *(const short8*)(qbase + 32);

    f32x4 cacc[4];
    #pragma unroll
    for (int nb = 0; nb < 4; ++nb) cacc[nb] = (f32x4)0.0f;
    float den = 0.0f;

    // preload kt=0
    gll16(gK,      K_s[0] + (w * 2 + 0) * 512);
    gll16(gK + 32, K_s[0] + (w * 2 + 1) * 512);
    gll16(gV,      V_s[0] + (w * 2 + 0) * 512);
    gll16(gV + 32, V_s[0] + (w * 2 + 1) * 512);

    for (int kt = 0; kt <= qt; ++kt) {
        const int cur = kt & 1;
        __syncthreads();                     // cur-buf loads done; prev reads done
        if (kt < qt) {
            const int nxt = cur ^ 1;
            const ushort* nK = gK + (kt + 1) * 4096;
            const ushort* nV = gV + (kt + 1) * 64;
            gll16(nK,      K_s[nxt] + (w * 2 + 0) * 512);
            gll16(nK + 32, K_s[nxt] + (w * 2 + 1) * 512);
            gll16(nV,      V_s[nxt] + (w * 2 + 0) * 512);
            gll16(nV + 32, V_s[nxt] + (w * 2 + 1) * 512);
        }
        // S^T phase: D[key][query] = K·Q
        #pragma unroll
        for (int nb = 0; nb < 4; ++nb) {
            const short8 kf0 = *(const short8*)(K_s[cur] + (nb * 2 + 0) * 512 + lane * 8);
            const short8 kf1 = *(const short8*)(K_s[cur] + (nb * 2 + 1) * 512 + lane * 8);
            f32x4 s = (f32x4)0.0f;
            s = __builtin_amdgcn_mfma_f32_16x16x32_bf16(kf0, qf0, s, 0, 0, 0);
            s = __builtin_amdgcn_mfma_f32_16x16x32_bf16(kf1, qf1, s, 0, 0, 0);
            const int k0g = kt * 64 + nb * 16 + quad * 4;
            ushort o[4];
            #pragma unroll
            for (int r = 0; r < 4; ++r) {
                float wgt = 0.0f;
                if (k0g + r <= qglob) wgt = __expf(s[r] * 0.2f);
                den += wgt;
                o[r] = f2bf(wgt);
            }
            // 4 consecutive keys, same query -> one 8B LDS write in A-frag order
            const int addr = (w * 2 + (nb >> 1)) * 512 +
                             ((nb & 1) * 2 + (quad >> 1)) * 128 +
                             m16 * 8 + (quad & 1) * 4;
            *(uint2*)(W_s + addr) = *(const uint2*)o;
        }
        __syncthreads();
        // PV: cacc += W · V
        const short8 wf0 = *(const short8*)(W_s + (w * 2 + 0) * 512 + lane * 8);
        const short8 wf1 = *(const short8*)(W_s + (w * 2 + 1) * 512 + lane * 8);
        #pragma unroll
        for (int nb = 0; nb < 4; ++nb) {
            const short8 vf0 = *(const short8*)(V_s[cur] + (nb * 2 + 0) * 512 + lane * 8);
            const short8 vf1 = *(const short8*)(V_s[cur] + (nb * 2 + 1) * 512 + lane * 8);
            cacc[nb] = __builtin_amdgcn_mfma_f32_16x16x32_bf16(wf0, vf0, cacc[nb], 0, 0, 0);
            cacc[nb] = __builtin_amdgcn_mfma_f32_16x16x32_bf16(wf1, vf1, cacc[nb], 0, 0, 0);
        }
    }

    // denominator: sum per query m16 across the 4 quads
    den += __shfl_xor(den, 16);
    den += __shfl_xor(den, 32);
    den_s[w][m16] = den;
    __syncthreads();
    float inv[4];
    #pragma unroll
    for (int r = 0; r < 4; ++r) inv[r] = 1.0f / den_s[w][quad * 4 + r];

    #pragma unroll
    for (int nb = 0; nb < 4; ++nb) {
        const int dim = h * 64 + nb * 16 + m16;
        #pragma unroll
        for (int r = 0; r < 4; ++r) {
            const int token = qt * 64 + w * 16 + quad * 4 + r;
            ctxb[(size_t)(b * 1024 + token) * D_MODEL + dim] = f2bf(cacc[nb][r] * inv[r]);
        }
    }
}

// ---------------------------------------------------------------------------
extern "C" void kernel_launch(void* const* d_in, const int* in_sizes, int n_in,
                              void* d_out, int out_size, void* d_ws, size_t ws_size,
                              hipStream_t stream)
{
    const float* x  = (const float*)d_in[0];
    const float* Wp = (const float*)d_in[1];
    const float* bp = (const float*)d_in[2];
    const float* Wv = (const float*)d_in[3];
    const float* Wo = (const float*)d_in[4];
    float* out = (float*)d_out;

    char* ws = (char*)d_ws;
    ushort* xb   = (ushort*)(ws);                 // 4 MB
    ushort* Wvt  = (ushort*)(ws + (4u  << 20));   // 2 MB
    ushort* Wot  = (ushort*)(ws + (6u  << 20));   // 2 MB
    ushort* Phi  = (ushort*)(ws + (8u  << 20));   // 4 MB
    ushort* Vt   = (ushort*)(ws + (12u << 20));   // 4 MB
    ushort* ctxb = (ushort*)(ws + (16u << 20));   // 4 MB
    ushort* Wpt  = (ushort*)(ws + (20u << 20));   // 160 KB

    prologue<<<3088, 256, 0, stream>>>(x, Wv, Wo, Wp, xb, Wvt, Wot, Wpt);
    mid_kernel<<<640, 256, 0, stream>>>(xb, Wvt, Wpt, bp, Vt, Phi);
    attn_mfma<<<dim3(16, 32), 256, 0, stream>>>(Phi, Vt, ctxb);
    gemm_out<<<dim3(16, 32), 256, 0, stream>>>(ctxb, Wot, out);
}